// Round 1
// baseline (153.562 us; speedup 1.0000x reference)
//
#include <hip/hip_runtime.h>

#define HW 2304          // 48*48
#define HW4 576          // HW/4
#define PART_STRIDE 2308 // 2304 A-partials + 1 sq, padded to mult of 4 (16B align)

// Stage 1: per-block partial sums. Each thread owns 4 fixed hw positions
// (one float4 per batch), so the |diff| accumulation needs no cross-lane
// traffic at all. Block reads a contiguous 9216B row per batch: perfectly
// coalesced.
__global__ __launch_bounds__(576) void sc_stage1(
    const float4* __restrict__ out4, const float4* __restrict__ tgt4,
    float* __restrict__ part, int B, int NB)
{
    int tid = threadIdx.x;
    int blk = blockIdx.x;
    float a0 = 0.f, a1 = 0.f, a2 = 0.f, a3 = 0.f, sq = 0.f;
    for (int b = blk; b < B; b += NB) {
        size_t base = (size_t)b * HW4 + tid;
        float4 o = out4[base];
        float4 t = tgt4[base];
        float d0 = o.x - t.x, d1 = o.y - t.y, d2 = o.z - t.z, d3 = o.w - t.w;
        sq = fmaf(d0, d0, sq);
        sq = fmaf(d1, d1, sq);
        sq = fmaf(d2, d2, sq);
        sq = fmaf(d3, d3, sq);
        a0 += fabsf(d0); a1 += fabsf(d1); a2 += fabsf(d2); a3 += fabsf(d3);
    }
    float* pbase = part + (size_t)blk * PART_STRIDE;
    ((float4*)pbase)[tid] = make_float4(a0, a1, a2, a3);

    // block-reduce sq (9 waves)
    #pragma unroll
    for (int off = 32; off; off >>= 1) sq += __shfl_down(sq, off);
    __shared__ float wsum[9];
    int wid = tid >> 6;
    if ((tid & 63) == 0) wsum[wid] = sq;
    __syncthreads();
    if (tid == 0) {
        float s = 0.f;
        #pragma unroll
        for (int w = 0; w < 9; ++w) s += wsum[w];
        pbase[HW] = s;
    }
}

// Stage 2: reduce NB partial rows -> A[2304] (normalized by B); block 36
// reduces the per-block sq sums and writes the MSE term to out[0] (plain
// store -> safe across graph replays without re-poison).
__global__ __launch_bounds__(64) void sc_stage2(
    const float* __restrict__ part, float* __restrict__ A,
    float* __restrict__ out, int NB, int B, float invN)
{
    int blk  = blockIdx.x;
    int lane = threadIdx.x;
    if (blk < 36) {
        int hw = blk * 64 + lane;      // lanes hit 64 consecutive hw: coalesced
        float s = 0.f;
        for (int r = 0; r < NB; ++r) s += part[(size_t)r * PART_STRIDE + hw];
        A[hw] = s / (float)B;
    } else {
        float s = 0.f;
        for (int r = lane; r < NB; r += 64) s += part[(size_t)r * PART_STRIDE + HW];
        #pragma unroll
        for (int off = 32; off; off >>= 1) s += __shfl_down(s, off);
        if (lane == 0) out[0] = s * invN;
    }
}

// Stage 3: one block per (i,j): l1 = (A . |psu_ij|)/HW, then
// out += 0.5*mu*l1^2 (54 atomic adds total; fp ordering noise ~1e-7).
__global__ __launch_bounds__(256) void sc_stage3(
    const float* __restrict__ A, const float* __restrict__ psu,
    const float* __restrict__ mu, float* __restrict__ out)
{
    int j = blockIdx.x;
    int tid = threadIdx.x;
    const float* p = psu + (size_t)j * HW;
    float s = 0.f;
    for (int hw = tid; hw < HW; hw += 256) s += A[hw] * fabsf(p[hw]);
    #pragma unroll
    for (int off = 32; off; off >>= 1) s += __shfl_down(s, off);
    __shared__ float wsum[4];
    if ((tid & 63) == 0) wsum[tid >> 6] = s;
    __syncthreads();
    if (tid == 0) {
        float l1 = (wsum[0] + wsum[1] + wsum[2] + wsum[3]) * (1.0f / HW);
        float contrib = 0.5f * mu[j] * l1 * l1;   // GAMMA = 1
        atomicAdd(out, contrib);
    }
}

extern "C" void kernel_launch(void* const* d_in, const int* in_sizes, int n_in,
                              void* d_out, int out_size, void* d_ws, size_t ws_size,
                              hipStream_t stream)
{
    const float* outp = (const float*)d_in[0];
    const float* tgtp = (const float*)d_in[1];
    const float* psu  = (const float*)d_in[2];
    const float* mu   = (const float*)d_in[3];

    int B   = in_sizes[0] / HW;     // 8192
    int nij = in_sizes[3];          // 54

    int NB = 512;                   // stage-1 blocks; shrink if ws too small
    while (NB > 1 &&
           ((size_t)NB * PART_STRIDE + HW) * sizeof(float) > ws_size)
        NB >>= 1;

    float* part = (float*)d_ws;
    float* A    = part + (size_t)NB * PART_STRIDE;
    float invN  = 1.0f / ((float)B * (float)HW);

    sc_stage1<<<NB, 576, 0, stream>>>((const float4*)outp, (const float4*)tgtp,
                                      part, B, NB);
    sc_stage2<<<37, 64, 0, stream>>>(part, A, (float*)d_out, NB, B, invN);
    sc_stage3<<<nij, 256, 0, stream>>>(A, psu, mu, (float*)d_out);
}

// Round 2
// 42.744 us; speedup vs baseline: 3.5926x; 3.5926x over previous
//
#include <hip/hip_runtime.h>

#define HW 2304          // 48*48
#define HW4 576          // HW/4
#define PART_STRIDE 2308 // 2304 A-partials + 1 sq, padded to mult of 4 (16B align)

// Stage 1: per-block partial sums. Each thread owns 4 fixed hw positions
// (one float4 per batch), so the |diff| accumulation needs no cross-lane
// traffic. Block reads a contiguous 9216B row per batch: perfectly coalesced.
__global__ __launch_bounds__(576) void sc_stage1(
    const float4* __restrict__ out4, const float4* __restrict__ tgt4,
    float* __restrict__ part, int B, int NB)
{
    int tid = threadIdx.x;
    int blk = blockIdx.x;
    float a0 = 0.f, a1 = 0.f, a2 = 0.f, a3 = 0.f, sq = 0.f;
    for (int b = blk; b < B; b += NB) {
        size_t base = (size_t)b * HW4 + tid;
        float4 o = out4[base];
        float4 t = tgt4[base];
        float d0 = o.x - t.x, d1 = o.y - t.y, d2 = o.z - t.z, d3 = o.w - t.w;
        sq = fmaf(d0, d0, sq);
        sq = fmaf(d1, d1, sq);
        sq = fmaf(d2, d2, sq);
        sq = fmaf(d3, d3, sq);
        a0 += fabsf(d0); a1 += fabsf(d1); a2 += fabsf(d2); a3 += fabsf(d3);
    }
    float* pbase = part + (size_t)blk * PART_STRIDE;
    ((float4*)pbase)[tid] = make_float4(a0, a1, a2, a3);

    // block-reduce sq (9 waves)
    #pragma unroll
    for (int off = 32; off; off >>= 1) sq += __shfl_down(sq, off);
    __shared__ float wsum[9];
    int wid = tid >> 6;
    if ((tid & 63) == 0) wsum[wid] = sq;
    __syncthreads();
    if (tid == 0) {
        float s = 0.f;
        #pragma unroll
        for (int w = 0; w < 9; ++w) s += wsum[w];
        pbase[HW] = s;
    }
}

// Stage 2 (v2): 36 column blocks x 1024 threads = 64 hw-lanes x 16 row-groups.
// Each thread sums NB/16 rows (serial chain 32 instead of 512); 16-way LDS
// reduce per hw. Block 36 reduces the per-block sq sums -> MSE into out[0]
// (plain store: idempotent across graph replays).
__global__ __launch_bounds__(1024) void sc_stage2(
    const float* __restrict__ part, float* __restrict__ A,
    float* __restrict__ out, int NB, int B, float invN)
{
    __shared__ float red[16][64];
    int lane = threadIdx.x & 63;
    int grp  = threadIdx.x >> 6;   // 0..15
    int blk  = blockIdx.x;
    if (blk < 36) {
        int hw = blk * 64 + lane;  // 64 consecutive floats per wave: coalesced
        float s = 0.f;
        for (int r = grp; r < NB; r += 16)
            s += part[(size_t)r * PART_STRIDE + hw];
        red[grp][lane] = s;
        __syncthreads();
        if (grp == 0) {
            float t = 0.f;
            #pragma unroll
            for (int g = 0; g < 16; ++g) t += red[g][lane];
            A[hw] = t / (float)B;
        }
    } else {
        // MSE term: NB (<=1024) per-block sq partials
        float s = (threadIdx.x < NB)
                    ? part[(size_t)threadIdx.x * PART_STRIDE + HW] : 0.f;
        #pragma unroll
        for (int off = 32; off; off >>= 1) s += __shfl_down(s, off);
        if ((threadIdx.x & 63) == 0) red[0][grp] = s;
        __syncthreads();
        if (threadIdx.x == 0) {
            float t = 0.f;
            #pragma unroll
            for (int g = 0; g < 16; ++g) t += red[0][g];
            out[0] = t * invN;
        }
    }
}

// Stage 3: one block per (i,j): l1 = (A . |psu_ij|)/HW, then
// out += 0.5*mu*l1^2 (54 atomic adds; fp ordering noise ~1e-7 << threshold).
__global__ __launch_bounds__(256) void sc_stage3(
    const float* __restrict__ A, const float* __restrict__ psu,
    const float* __restrict__ mu, float* __restrict__ out)
{
    int j = blockIdx.x;
    int tid = threadIdx.x;
    const float* p = psu + (size_t)j * HW;
    float s = 0.f;
    for (int hw = tid; hw < HW; hw += 256) s += A[hw] * fabsf(p[hw]);
    #pragma unroll
    for (int off = 32; off; off >>= 1) s += __shfl_down(s, off);
    __shared__ float wsum[4];
    if ((tid & 63) == 0) wsum[tid >> 6] = s;
    __syncthreads();
    if (tid == 0) {
        float l1 = (wsum[0] + wsum[1] + wsum[2] + wsum[3]) * (1.0f / HW);
        float contrib = 0.5f * mu[j] * l1 * l1;   // GAMMA = 1
        atomicAdd(out, contrib);
    }
}

extern "C" void kernel_launch(void* const* d_in, const int* in_sizes, int n_in,
                              void* d_out, int out_size, void* d_ws, size_t ws_size,
                              hipStream_t stream)
{
    const float* outp = (const float*)d_in[0];
    const float* tgtp = (const float*)d_in[1];
    const float* psu  = (const float*)d_in[2];
    const float* mu   = (const float*)d_in[3];

    int B   = in_sizes[0] / HW;     // 8192
    int nij = in_sizes[3];          // 54

    int NB = 512;                   // stage-1 blocks; shrink if ws too small
    while (NB > 16 &&
           ((size_t)NB * PART_STRIDE + HW) * sizeof(float) > ws_size)
        NB >>= 1;

    float* part = (float*)d_ws;
    float* A    = part + (size_t)NB * PART_STRIDE;
    float invN  = 1.0f / ((float)B * (float)HW);

    sc_stage1<<<NB, 576, 0, stream>>>((const float4*)outp, (const float4*)tgtp,
                                      part, B, NB);
    sc_stage2<<<37, 1024, 0, stream>>>(part, A, (float*)d_out, NB, B, invN);
    sc_stage3<<<nij, 256, 0, stream>>>(A, psu, mu, (float*)d_out);
}